// Round 3
// baseline (202.918 us; speedup 1.0000x reference)
//
#include <hip/hip_runtime.h>

// SSIM fused, v12: vertical-strip waves + granule pipeline.
// v11 post-mortem: spill fixed (WRITE 92MB->0.2MB) but dur stuck at 53us =
// v9's number despite occupancy 32->65%. VGPR_Count=32 again: compiler sank
// loads to uses, so each tile still eats a serial HBM latency, and per-wave
// overhead (band build: 8 ds_bpermute+40 VALU; 6-shuffle serial reduce ~700cy)
// is paid by every 32-row tile. All pipes <=26% -> latency-bound.
// v12: each wave walks a 128-row strip of its 16-col tile (8 output granules
// of 16 rows; 9 input granules):
//   - vertical reuse: adjacent output granules share an H input granule ->
//     steady state 1 load + 1 h + 1 v per output granule (was 1.5/1.5/1).
//   - band + reduce amortized 4x (once per 8 granules, not per 2).
//   - 2-deep load pipeline: granule k+2's 4 float4 issue before v-pass(k),
//     rotating two statically-named 16-VGPR buffers (La/Lb). One
//     sched_barrier(0) after each load-issue pins loads early (v10/v11's
//     failure was the compiler sinking them).
//   - grid 8x4x48 = 1536 blocks = exactly 6/CU (one residency round);
//     __launch_bounds__(256,6) -> 80-VGPR cap, peak ~70 live.
// H ring unchanged: 2 slots, granule g -> slot g&1; v-pass window start
// (quad*8 + o*16)&31 (formula generalizes; verified). LDS 20480 B.

#define IMG 512
#define NPIX (16LL * 3 * 512 * 512)
#define GX 8                  /* 32 col-tiles / 4 waves per block */
#define GY 4                  /* 512 rows / 128 rows per wave */
#define NG 8                  /* output granules (16 rows) per wave */
#define NBLK (GX * GY * 48)   /* 1536 blocks */
#define NPART NBLK            /* one float per block: 6 KB */

typedef short v8s __attribute__((ext_vector_type(8)));   // 8 x bf16 (4 VGPRs)
typedef float v4f __attribute__((ext_vector_type(4)));   // MFMA accumulator
typedef __bf16 bf2 __attribute__((ext_vector_type(2)));
typedef float f2  __attribute__((ext_vector_type(2)));

static __device__ __forceinline__ int cvtpk2(f2 v) {     // v_cvt_pk_bf16_f32
    bf2 r = __builtin_convertvector(v, bf2);
    return __builtin_bit_cast(int, r);
}
static __device__ __forceinline__ unsigned f2bf(float f) {
    unsigned u = __float_as_uint(f);
    return (u + 0x7FFFu + ((u >> 16) & 1u)) >> 16;
}

// Load one 16-row input granule: 4 float4 (L = {a0,a1,b0,b1}).
static __device__ __forceinline__ void load_g(
    const float* __restrict__ p1, const float* __restrict__ p2,
    int grow, int gcol, bool edge, float4 (&L)[4])
{
    if (!edge) {
        const float* r1 = p1 + (size_t)grow * IMG + gcol;
        const float* r2 = p2 + (size_t)grow * IMG + gcol;
        L[0] = *(const float4*)r1;       L[1] = *(const float4*)(r1 + 4);
        L[2] = *(const float4*)r2;       L[3] = *(const float4*)(r2 + 4);
    } else {
        float4 z4; z4.x = z4.y = z4.z = z4.w = 0.f;
        L[0] = L[1] = L[2] = L[3] = z4;
        if ((unsigned)grow < IMG) {
            const float* r1 = p1 + (size_t)grow * IMG;
            const float* r2 = p2 + (size_t)grow * IMG;
            if ((unsigned)gcol < IMG) {
                L[0] = *(const float4*)(r1 + gcol);
                L[2] = *(const float4*)(r2 + gcol);
            }
            if ((unsigned)(gcol + 4) < IMG) {
                L[1] = *(const float4*)(r1 + gcol + 4);
                L[3] = *(const float4*)(r2 + gcol + 4);
            }
        }
    }
}

// h-pass for one 16-row granule: pack 4 planes to bf16, 4 MFMA, write ring slot.
static __device__ __forceinline__ void h_rt(
    const float4 (&L)[4], v8s band, short (*hw)[16][40], int lm, int quad, int slot)
{
    const v4f zacc = {0.f, 0.f, 0.f, 0.f};
    const float4 a0 = L[0], a1 = L[1], b0 = L[2], b1 = L[3];
    f2 a0l; a0l.x = a0.x; a0l.y = a0.y;   f2 a0h; a0h.x = a0.z; a0h.y = a0.w;
    f2 a1l; a1l.x = a1.x; a1l.y = a1.y;   f2 a1h; a1h.x = a1.z; a1h.y = a1.w;
    f2 b0l; b0l.x = b0.x; b0l.y = b0.y;   f2 b0h; b0h.x = b0.z; b0h.y = b0.w;
    f2 b1l; b1l.x = b1.x; b1l.y = b1.y;   f2 b1h; b1h.x = b1.z; b1h.y = b1.w;

    v8s A[4]; int4 w;
    w.x = cvtpk2(a0l); w.y = cvtpk2(a0h); w.z = cvtpk2(a1l); w.w = cvtpk2(a1h);
    A[0] = __builtin_bit_cast(v8s, w);
    w.x = cvtpk2(b0l); w.y = cvtpk2(b0h); w.z = cvtpk2(b1l); w.w = cvtpk2(b1h);
    A[1] = __builtin_bit_cast(v8s, w);
    w.x = cvtpk2(__builtin_elementwise_fma(a0l, a0l, b0l * b0l));
    w.y = cvtpk2(__builtin_elementwise_fma(a0h, a0h, b0h * b0h));
    w.z = cvtpk2(__builtin_elementwise_fma(a1l, a1l, b1l * b1l));
    w.w = cvtpk2(__builtin_elementwise_fma(a1h, a1h, b1h * b1h));
    A[2] = __builtin_bit_cast(v8s, w);
    w.x = cvtpk2(a0l * b0l); w.y = cvtpk2(a0h * b0h);
    w.z = cvtpk2(a1l * b1l); w.w = cvtpk2(a1h * b1h);
    A[3] = __builtin_bit_cast(v8s, w);

    #pragma unroll
    for (int p = 0; p < 4; ++p) {
        const v4f acc = __builtin_amdgcn_mfma_f32_16x16x32_bf16(A[p], band, zacc, 0, 0, 0);
        // D C-layout: col = lm, rows quad*4 + reg -> ring slot, col-major write.
        int2 w2;
        f2 lo; lo.x = acc[0]; lo.y = acc[1];
        f2 hi; hi.x = acc[2]; hi.y = acc[3];
        w2.x = cvtpk2(lo); w2.y = cvtpk2(hi);
        *(int2*)&hw[p][lm][slot * 16 + quad * 4] = w2;
    }
}

// v-pass for output granule o (ring window = granules o, o+1) + SSIM accumulate.
static __device__ __forceinline__ void v_t2(
    v8s band, short (*hw)[16][40], int lm, int quad, int o, f2& vsum)
{
    const v4f zacc = {0.f, 0.f, 0.f, 0.f};
    const int bs = (quad * 8 + o * 16) & 31;   // granule g lives at slot g&1
    v4f acc[4];
    #pragma unroll
    for (int p = 0; p < 4; ++p) {
        const v8s hf = *(const v8s*)&hw[p][lm][bs];
        acc[p] = __builtin_amdgcn_mfma_f32_16x16x32_bf16(band, hf, zacc, 0, 0, 0);
    }
    const f2 C1v = {1e-4f, 1e-4f};        // 0.01^2
    const f2 C2v = {9e-4f, 9e-4f};        // 0.03^2
    const f2 two = {2.f, 2.f};
    #pragma unroll
    for (int h = 0; h < 2; ++h) {
        f2 m1; m1.x = acc[0][2 * h]; m1.y = acc[0][2 * h + 1];
        f2 m2; m2.x = acc[1][2 * h]; m2.y = acc[1][2 * h + 1];
        f2 es; es.x = acc[2][2 * h]; es.y = acc[2][2 * h + 1];
        f2 ex; ex.x = acc[3][2 * h]; ex.y = acc[3][2 * h + 1];
        const f2 m1s = m1 * m1, m2s = m2 * m2, m12 = m1 * m2;
        const f2 sig = es - m1s - m2s;                  // sig1_sq + sig2_sq
        const f2 s12 = ex - m12;
        const f2 num = __builtin_elementwise_fma(two, m12, C1v) *
                       __builtin_elementwise_fma(two, s12, C2v);
        const f2 den = (m1s + m2s + C1v) * (sig + C2v);
        f2 r; r.x = __builtin_amdgcn_rcpf(den.x); r.y = __builtin_amdgcn_rcpf(den.y);
        vsum = __builtin_elementwise_fma(num, r, vsum);
    }
}

__global__ __launch_bounds__(256, 6) void ssim_kernel(
    const float* __restrict__ img1,
    const float* __restrict__ img2,
    const float* __restrict__ win,
    float* __restrict__ partial)
{
    // Per-wave private ring: [wave][plane][col][40 shorts]. 20480 B.
    // Shorts 0-31 = two 16-row slots; 32-39 = pad (final reduce borrows
    // shorts 36-37 of [3][15] as a per-wave float slot).
    __shared__ __align__(16) short hb[4][4][16][40];

    const int tid  = threadIdx.x;
    const int lane = tid & 63;
    const int wave = tid >> 6;
    const int lm   = lane & 15;
    const int quad = lane >> 4;

    const int bx = blockIdx.x, by = blockIdx.y, z = blockIdx.z;
    const int rowbase = by * (NG * 16);

    // Band fragment via shuffle: value g[k-i-3], i = lane&15, k = quad*8+j.
    float gl = 0.f;
    if (lane < 11) gl = win[55 + lane] * rsqrtf(win[60]);
    v8s band;
    #pragma unroll
    for (int j = 0; j < 8; ++j) {
        const int t  = quad * 8 + j - lm - 3;
        const int tc = ((unsigned)t > 10u) ? 11 : t;   // lane 11 holds 0
        band[j] = (short)f2bf(__shfl(gl, tc));
    }

    const size_t zoff = (size_t)z * IMG * IMG;
    const float* p1 = img1 + zoff;
    const float* p2 = img2 + zoff;

    // One 16-col tile per wave, 128-row strip.
    const int gct = bx * 4 + wave;
    const bool colOK = (gct > 0) & (gct < 31);
    const int gcol = gct * 16 - 8 + quad * 8;          // 4-aligned
    short (*hw)[16][40] = hb[wave];

    // Granule k (k=0..NG): input rows [rowbase + 16k - 8, +16).
    // Row-edge only at k==0 (by==0) and k==NG (by==GY-1).
    const bool topE = (by == 0), botE = (by == GY - 1);
    #define EDGE_K(k) (!colOK | ((k) == 0 ? topE : false) | ((k) == NG ? botE : false))
    #define GROW(k)   (rowbase + (k) * 16 - 8 + lm)

    float4 La[4], Lb[4];
    f2 vsum = {0.f, 0.f};

    // Prologue: granules 0,1 in flight; h(0) waits only on the first 4 loads.
    load_g(p1, p2, GROW(0), gcol, EDGE_K(0), La);
    load_g(p1, p2, GROW(1), gcol, EDGE_K(1), Lb);
    h_rt(La, band, hw, lm, quad, 0);

    // Steady state per output granule o: prefetch granule o+2 (consumed next
    // iteration -> its HBM latency hides under this iteration's h+v),
    // h(granule o+1), v(o). Slot (o+1)&1 overwrite happens after v(o-1)'s
    // last read (program order; same-wave LDS is in-order on aliased addrs).
    #pragma unroll
    for (int o = 0; o < NG; o += 2) {
        load_g(p1, p2, GROW(o + 2), gcol, EDGE_K(o + 2), La);
        __builtin_amdgcn_sched_barrier(0);     // keep prefetch issued early
        h_rt(Lb, band, hw, lm, quad, (o + 1) & 1);
        v_t2(band, hw, lm, quad, o, vsum);

        if (o + 3 <= NG)
            load_g(p1, p2, GROW(o + 3), gcol, EDGE_K(o + 3), Lb);
        __builtin_amdgcn_sched_barrier(0);
        h_rt(La, band, hw, lm, quad, (o + 2) & 1);
        v_t2(band, hw, lm, quad, o + 1, vsum);
    }
    #undef EDGE_K
    #undef GROW

    // ---- wave reduction, then per-BLOCK partial via LDS pad slots ----
    float vs = vsum.x + vsum.y;
    #pragma unroll
    for (int off = 32; off > 0; off >>= 1)
        vs += __shfl_down(vs, off, 64);
    if (lane == 0) *(float*)&hb[wave][3][15][36] = vs;   // pad, wave-private
    __syncthreads();
    if (tid == 0) {
        float t = 0.f;
        #pragma unroll
        for (int w = 0; w < 4; ++w) t += *(const float*)&hb[w][3][15][36];
        partial[(z * GY + by) * GX + bx] = t;
    }
}

__global__ __launch_bounds__(512) void finalize_kernel(
    const float* __restrict__ partial, float* __restrict__ out)
{
    __shared__ float red[8];
    float s = 0.f;
    if (threadIdx.x < NPART / 4) {                      // 384 float4s
        const float4 t = ((const float4*)partial)[threadIdx.x];
        s = (t.x + t.y) + (t.z + t.w);
    }
    #pragma unroll
    for (int off = 32; off > 0; off >>= 1)
        s += __shfl_down(s, off, 64);
    if ((threadIdx.x & 63) == 0) red[threadIdx.x >> 6] = s;
    __syncthreads();
    if (threadIdx.x == 0) {
        float t = 0.f;
        #pragma unroll
        for (int i = 0; i < 8; ++i) t += red[i];
        out[0] = 1.0f - t / (float)NPIX;
    }
}

extern "C" void kernel_launch(void* const* d_in, const int* in_sizes, int n_in,
                              void* d_out, int out_size, void* d_ws, size_t ws_size,
                              hipStream_t stream) {
    const float* img1 = (const float*)d_in[0];
    const float* img2 = (const float*)d_in[1];
    const float* win  = (const float*)d_in[2];
    float* partialb = (float*)d_ws;  // NPART floats = 6 KB; fully rewritten each call

    dim3 grid(GX, GY, 48);
    ssim_kernel<<<grid, dim3(256), 0, stream>>>(img1, img2, win, partialb);
    finalize_kernel<<<1, dim3(512), 0, stream>>>(partialb, (float*)d_out);
}

// Round 4
// 136.778 us; speedup vs baseline: 1.4836x; 1.4836x over previous
//
#include <hip/hip_runtime.h>

// SSIM fused, v13: async LDS staging via global_load_lds + counted vmcnt.
// v12 post-mortem: register pipeline spilled AGAIN (WRITE 146MB, dur 116us).
// Three failures (v10/v11/v12) prove the allocator will not hold a load
// window in VGPRs. v13 removes registers from the staging path entirely:
//   - 3-slot per-wave raw ring in LDS; granule = 4x global_load_lds
//     (16B/lane, identity layout lane i -> base + i*16; readback
//     ds_read_b128 at lane*16 = canonical conflict-free pattern).
//   - Counted waits: steady state keeps 2 granules (8 loads) in flight,
//     s_waitcnt vmcnt(8); tail 4 then 0. Never drains mid-loop (T4).
//   - Edge handling made UNIFORM: clamp row/col addresses into the image,
//     zero-fix registers after readback under a wave-uniform branch.
//   - Keeps v12's verified strip math: 128-row strip/wave, 9 input granules,
//     vertical H reuse, 2-slot H ring (slot g&1, window (quad*8+o*16)&31),
//     band/reduce amortized 8x.
//   - LDS: raw 48KB + H 20KB = 68KB/block -> 2 blocks/CU (25% occ; v9 vs
//     v11 showed 32% vs 65% occ = same 53us, so occupancy is not the lever;
//     per-wave async depth is). VGPR ~48, nothing to spill.

#define IMG 512
#define NPIX (16LL * 3 * 512 * 512)
#define GX 8                  /* 32 col-tiles / 4 waves per block */
#define GY 4                  /* 512 rows / 128 rows per wave */
#define NG 8                  /* output granules (16 rows) per wave */
#define NBLK (GX * GY * 48)   /* 1536 blocks */
#define NPART NBLK            /* one float per block: 6 KB */

typedef short v8s __attribute__((ext_vector_type(8)));   // 8 x bf16 (4 VGPRs)
typedef float v4f __attribute__((ext_vector_type(4)));   // MFMA accumulator
typedef __bf16 bf2 __attribute__((ext_vector_type(2)));
typedef float f2  __attribute__((ext_vector_type(2)));

static __device__ __forceinline__ int cvtpk2(f2 v) {     // v_cvt_pk_bf16_f32
    bf2 r = __builtin_convertvector(v, bf2);
    return __builtin_bit_cast(int, r);
}
static __device__ __forceinline__ unsigned f2bf(float f) {
    unsigned u = __float_as_uint(f);
    return (u + 0x7FFFu + ((u >> 16) & 1u)) >> 16;
}

// Async 16B/lane global->LDS. Dest is wave-uniform base; lane i lands at
// base + i*16. Source address is per-lane.
static __device__ __forceinline__ void gload16(const float* g, void* lds) {
    __builtin_amdgcn_global_load_lds(
        (const __attribute__((address_space(1))) void*)g,
        (__attribute__((address_space(3))) void*)lds, 16, 0, 0);
}

template <int N>
static __device__ __forceinline__ void vwait() {
    if constexpr (N == 8)      asm volatile("s_waitcnt vmcnt(8)" ::: "memory");
    else if constexpr (N == 4) asm volatile("s_waitcnt vmcnt(4)" ::: "memory");
    else                       asm volatile("s_waitcnt vmcnt(0)" ::: "memory");
    __builtin_amdgcn_sched_barrier(0);   // keep ds_reads below the wait
}

// h-pass for one 16-row granule: pack 4 planes to bf16, 4 MFMA, write H ring.
static __device__ __forceinline__ void h_rt(
    const float4 (&L)[4], v8s band, short (*hw)[16][40], int lm, int quad, int slot)
{
    const v4f zacc = {0.f, 0.f, 0.f, 0.f};
    const float4 a0 = L[0], a1 = L[1], b0 = L[2], b1 = L[3];
    f2 a0l; a0l.x = a0.x; a0l.y = a0.y;   f2 a0h; a0h.x = a0.z; a0h.y = a0.w;
    f2 a1l; a1l.x = a1.x; a1l.y = a1.y;   f2 a1h; a1h.x = a1.z; a1h.y = a1.w;
    f2 b0l; b0l.x = b0.x; b0l.y = b0.y;   f2 b0h; b0h.x = b0.z; b0h.y = b0.w;
    f2 b1l; b1l.x = b1.x; b1l.y = b1.y;   f2 b1h; b1h.x = b1.z; b1h.y = b1.w;

    v8s A[4]; int4 w;
    w.x = cvtpk2(a0l); w.y = cvtpk2(a0h); w.z = cvtpk2(a1l); w.w = cvtpk2(a1h);
    A[0] = __builtin_bit_cast(v8s, w);
    w.x = cvtpk2(b0l); w.y = cvtpk2(b0h); w.z = cvtpk2(b1l); w.w = cvtpk2(b1h);
    A[1] = __builtin_bit_cast(v8s, w);
    w.x = cvtpk2(__builtin_elementwise_fma(a0l, a0l, b0l * b0l));
    w.y = cvtpk2(__builtin_elementwise_fma(a0h, a0h, b0h * b0h));
    w.z = cvtpk2(__builtin_elementwise_fma(a1l, a1l, b1l * b1l));
    w.w = cvtpk2(__builtin_elementwise_fma(a1h, a1h, b1h * b1h));
    A[2] = __builtin_bit_cast(v8s, w);
    w.x = cvtpk2(a0l * b0l); w.y = cvtpk2(a0h * b0h);
    w.z = cvtpk2(a1l * b1l); w.w = cvtpk2(a1h * b1h);
    A[3] = __builtin_bit_cast(v8s, w);

    #pragma unroll
    for (int p = 0; p < 4; ++p) {
        const v4f acc = __builtin_amdgcn_mfma_f32_16x16x32_bf16(A[p], band, zacc, 0, 0, 0);
        // D C-layout: col = lm, rows quad*4 + reg -> ring slot, col-major write.
        int2 w2;
        f2 lo; lo.x = acc[0]; lo.y = acc[1];
        f2 hi; hi.x = acc[2]; hi.y = acc[3];
        w2.x = cvtpk2(lo); w2.y = cvtpk2(hi);
        *(int2*)&hw[p][lm][slot * 16 + quad * 4] = w2;
    }
}

// v-pass for output granule o (ring window = granules o, o+1) + SSIM accumulate.
static __device__ __forceinline__ void v_t2(
    v8s band, short (*hw)[16][40], int lm, int quad, int o, f2& vsum)
{
    const v4f zacc = {0.f, 0.f, 0.f, 0.f};
    const int bs = (quad * 8 + o * 16) & 31;   // granule g lives at H slot g&1
    v4f acc[4];
    #pragma unroll
    for (int p = 0; p < 4; ++p) {
        const v8s hf = *(const v8s*)&hw[p][lm][bs];
        acc[p] = __builtin_amdgcn_mfma_f32_16x16x32_bf16(band, hf, zacc, 0, 0, 0);
    }
    const f2 C1v = {1e-4f, 1e-4f};        // 0.01^2
    const f2 C2v = {9e-4f, 9e-4f};        // 0.03^2
    const f2 two = {2.f, 2.f};
    #pragma unroll
    for (int h = 0; h < 2; ++h) {
        f2 m1; m1.x = acc[0][2 * h]; m1.y = acc[0][2 * h + 1];
        f2 m2; m2.x = acc[1][2 * h]; m2.y = acc[1][2 * h + 1];
        f2 es; es.x = acc[2][2 * h]; es.y = acc[2][2 * h + 1];
        f2 ex; ex.x = acc[3][2 * h]; ex.y = acc[3][2 * h + 1];
        const f2 m1s = m1 * m1, m2s = m2 * m2, m12 = m1 * m2;
        const f2 sig = es - m1s - m2s;                  // sig1_sq + sig2_sq
        const f2 s12 = ex - m12;
        const f2 num = __builtin_elementwise_fma(two, m12, C1v) *
                       __builtin_elementwise_fma(two, s12, C2v);
        const f2 den = (m1s + m2s + C1v) * (sig + C2v);
        f2 r; r.x = __builtin_amdgcn_rcpf(den.x); r.y = __builtin_amdgcn_rcpf(den.y);
        vsum = __builtin_elementwise_fma(num, r, vsum);
    }
}

__global__ __launch_bounds__(256, 2) void ssim_kernel(
    const float* __restrict__ img1,
    const float* __restrict__ img2,
    const float* __restrict__ win,
    float* __restrict__ partial)
{
    // H ring: [wave][plane][col][40 shorts] = 20480 B (shorts 0-31 = two
    // 16-row slots; pad 32-39; final reduce borrows shorts 36-37 of [3][15]).
    __shared__ __align__(16) short hb[4][4][16][40];
    // Raw ring: [wave][slot][chunk][lane] float4 = 49152 B. Identity layout:
    // chunk c of granule (k%3) holds lane i's 16B at [c][i].
    __shared__ __align__(16) float4 raw[4][3][4][64];

    const int tid  = threadIdx.x;
    const int lane = tid & 63;
    const int wave = tid >> 6;
    const int lm   = lane & 15;
    const int quad = lane >> 4;

    const int bx = blockIdx.x, by = blockIdx.y, z = blockIdx.z;
    const int rowbase = by * (NG * 16);

    // Band fragment via shuffle: value g[k-i-3], i = lane&15, k = quad*8+j.
    float gl = 0.f;
    if (lane < 11) gl = win[55 + lane] * rsqrtf(win[60]);
    v8s band;
    #pragma unroll
    for (int j = 0; j < 8; ++j) {
        const int t  = quad * 8 + j - lm - 3;
        const int tc = ((unsigned)t > 10u) ? 11 : t;   // lane 11 holds 0
        band[j] = (short)f2bf(__shfl(gl, tc));
    }

    const size_t zoff = (size_t)z * IMG * IMG;
    const float* p1 = img1 + zoff;
    const float* p2 = img2 + zoff;

    // One 16-col tile per wave, 128-row strip.
    const int gct = bx * 4 + wave;
    const bool colOK = (gct > 0) & (gct < 31);
    const int gcol = gct * 16 - 8 + quad * 8;          // -8 .. 512
    // Clamped column addresses (always in-image) + badness flags for zero-fix.
    const int  colA = gcol < 0 ? 0 : (gcol > IMG - 4 ? IMG - 4 : gcol);
    const int  colB = (gcol + 4) < 0 ? 0 : ((gcol + 4) > IMG - 4 ? IMG - 4 : (gcol + 4));
    const bool cbA  = (unsigned)gcol >= (unsigned)IMG;
    const bool cbB  = (unsigned)(gcol + 4) >= (unsigned)IMG;
    const bool topE = (by == 0), botE = (by == GY - 1);
    short (*hw)[16][40] = hb[wave];

    // Issue granule k's 4 async loads into raw slot (row clamped in-image).
    auto issue_g = [&](int k, int slot) {
        const int gr  = rowbase + k * 16 - 8 + lm;
        const int grc = gr < 0 ? 0 : (gr > IMG - 1 ? IMG - 1 : gr);
        const float* r1 = p1 + (size_t)grc * IMG;
        const float* r2 = p2 + (size_t)grc * IMG;
        gload16(r1 + colA, &raw[wave][slot][0][0]);
        gload16(r1 + colB, &raw[wave][slot][1][0]);
        gload16(r2 + colA, &raw[wave][slot][2][0]);
        gload16(r2 + colB, &raw[wave][slot][3][0]);
    };
    // Read granule k back (caller already waited), zero-fix edges, h-pass.
    auto consume_h = [&](int k, int slot) {
        float4 L[4];
        L[0] = raw[wave][slot][0][lane];
        L[1] = raw[wave][slot][1][lane];
        L[2] = raw[wave][slot][2][lane];
        L[3] = raw[wave][slot][3][lane];
        const bool rowsE = (k == 0 && topE) || (k == NG && botE);
        if (!colOK || rowsE) {                     // wave-uniform branch
            const int gr = rowbase + k * 16 - 8 + lm;
            const bool rbad = (unsigned)gr >= (unsigned)IMG;
            float4 zz; zz.x = zz.y = zz.z = zz.w = 0.f;
            if (rbad | cbA) { L[0] = zz; L[2] = zz; }
            if (rbad | cbB) { L[1] = zz; L[3] = zz; }
        }
        h_rt(L, band, hw, lm, quad, k & 1);
    };

    f2 vsum = {0.f, 0.f};
    // Pipeline: 3 granules in flight; consume waits vmcnt(8) (2 newer
    // granules = 8 loads stay outstanding), tail 4 then 0. WAR on raw slots
    // is safe: slot s is re-issued 2 full iterations after its last ds_read
    // (whose lgkmcnt drained before the h-pass used the data).
    issue_g(0, 0); issue_g(1, 1); issue_g(2, 2);
    vwait<8>(); consume_h(0, 0);
    issue_g(3, 0); vwait<8>(); consume_h(1, 1); v_t2(band, hw, lm, quad, 0, vsum);
    issue_g(4, 1); vwait<8>(); consume_h(2, 2); v_t2(band, hw, lm, quad, 1, vsum);
    issue_g(5, 2); vwait<8>(); consume_h(3, 0); v_t2(band, hw, lm, quad, 2, vsum);
    issue_g(6, 0); vwait<8>(); consume_h(4, 1); v_t2(band, hw, lm, quad, 3, vsum);
    issue_g(7, 1); vwait<8>(); consume_h(5, 2); v_t2(band, hw, lm, quad, 4, vsum);
    issue_g(8, 2); vwait<8>(); consume_h(6, 0); v_t2(band, hw, lm, quad, 5, vsum);
                   vwait<4>(); consume_h(7, 1); v_t2(band, hw, lm, quad, 6, vsum);
                   vwait<0>(); consume_h(8, 2); v_t2(band, hw, lm, quad, 7, vsum);

    // ---- wave reduction, then per-BLOCK partial via LDS pad slots ----
    float vs = vsum.x + vsum.y;
    #pragma unroll
    for (int off = 32; off > 0; off >>= 1)
        vs += __shfl_down(vs, off, 64);
    if (lane == 0) *(float*)&hb[wave][3][15][36] = vs;   // pad, wave-private
    __syncthreads();
    if (tid == 0) {
        float t = 0.f;
        #pragma unroll
        for (int w = 0; w < 4; ++w) t += *(const float*)&hb[w][3][15][36];
        partial[(z * GY + by) * GX + bx] = t;
    }
}

__global__ __launch_bounds__(512) void finalize_kernel(
    const float* __restrict__ partial, float* __restrict__ out)
{
    __shared__ float red[8];
    float s = 0.f;
    if (threadIdx.x < NPART / 4) {                      // 384 float4s
        const float4 t = ((const float4*)partial)[threadIdx.x];
        s = (t.x + t.y) + (t.z + t.w);
    }
    #pragma unroll
    for (int off = 32; off > 0; off >>= 1)
        s += __shfl_down(s, off, 64);
    if ((threadIdx.x & 63) == 0) red[threadIdx.x >> 6] = s;
    __syncthreads();
    if (threadIdx.x == 0) {
        float t = 0.f;
        #pragma unroll
        for (int i = 0; i < 8; ++i) t += red[i];
        out[0] = 1.0f - t / (float)NPIX;
    }
}

extern "C" void kernel_launch(void* const* d_in, const int* in_sizes, int n_in,
                              void* d_out, int out_size, void* d_ws, size_t ws_size,
                              hipStream_t stream) {
    const float* img1 = (const float*)d_in[0];
    const float* img2 = (const float*)d_in[1];
    const float* win  = (const float*)d_in[2];
    float* partialb = (float*)d_ws;  // NPART floats = 6 KB; fully rewritten each call

    dim3 grid(GX, GY, 48);
    ssim_kernel<<<grid, dim3(256), 0, stream>>>(img1, img2, win, partialb);
    finalize_kernel<<<1, dim3(512), 0, stream>>>(partialb, (float*)d_out);
}